// Round 1
// baseline (492.832 us; speedup 1.0000x reference)
//
#include <hip/hip_runtime.h>
#include <hip/hip_bf16.h>

#define B_   8
#define SQ_  2048
#define SK_  2048
#define D_   1024
#define DV_  1024

typedef __bf16 bf16;
typedef __attribute__((ext_vector_type(4))) __bf16 bf16x4;
typedef __attribute__((ext_vector_type(8))) __bf16 bf16x8;
typedef __attribute__((ext_vector_type(4))) float  f32x4;

typedef const __attribute__((address_space(1))) void* gptr1;
typedef __attribute__((address_space(3))) void*       lptr3;

__device__ __forceinline__ void gload16(const void* g, void* l) {
    // async global->LDS, 16B/lane. LDS dest must be lane-linear within the wave.
    __builtin_amdgcn_global_load_lds((gptr1)g, (lptr3)l, 16, 0, 0);
}

// ---------------------------------------------------------------------------
// K0a: fp32 -> bf16 convert for Q and K (blockIdx.y selects matrix).
// 8 elements/thread, fully coalesced.
// ---------------------------------------------------------------------------
__global__ __launch_bounds__(256)
void convert_kernel(const float* __restrict__ A, const float* __restrict__ Bm,
                    bf16* __restrict__ dA, bf16* __restrict__ dB)
{
    const float* src = blockIdx.y ? Bm : A;
    bf16*        dst = blockIdx.y ? dB : dA;
    size_t i = ((size_t)blockIdx.x * 256 + threadIdx.x) * 8;
    float4 v0 = *(const float4*)(src + i);
    float4 v1 = *(const float4*)(src + i + 4);
    bf16x8 o = { (bf16)v0.x, (bf16)v0.y, (bf16)v0.z, (bf16)v0.w,
                 (bf16)v1.x, (bf16)v1.y, (bf16)v1.z, (bf16)v1.w };
    *(bf16x8*)(dst + i) = o;
}

// ---------------------------------------------------------------------------
// K0b: V (B,SK,DV) fp32 -> VT (B,DV,SK) bf16, 64x64 LDS tile transpose.
// Coalesced reads, 16B-chunk writes.
// ---------------------------------------------------------------------------
__global__ __launch_bounds__(256)
void convVT_kernel(const float* __restrict__ V, bf16* __restrict__ VT)
{
    const int b  = blockIdx.z;
    const int k0 = blockIdx.x * 64;
    const int n0 = blockIdx.y * 64;
    __shared__ bf16 T[64][72];                       // [k][n], padded

    const int tid = threadIdx.x;
    #pragma unroll
    for (int i = 0; i < 4; ++i) {                    // 64 rows x 16 float4
        int s  = tid + i * 256;
        int r  = s >> 4;
        int c4 = (s & 15) << 2;
        float4 v = *(const float4*)(V + ((size_t)b * SK_ + (k0 + r)) * DV_ + n0 + c4);
        T[r][c4 + 0] = (bf16)v.x;
        T[r][c4 + 1] = (bf16)v.y;
        T[r][c4 + 2] = (bf16)v.z;
        T[r][c4 + 3] = (bf16)v.w;
    }
    __syncthreads();
    #pragma unroll
    for (int i = 0; i < 2; ++i) {                    // 64 out-rows x 8 chunks
        int s  = tid + i * 256;
        int n  = s >> 3;
        int c8 = (s & 7) << 3;
        bf16x8 o;
        #pragma unroll
        for (int j = 0; j < 8; ++j) o[j] = T[c8 + j][n];
        *(bf16x8*)(VT + ((size_t)b * DV_ + (n0 + n)) * SK_ + k0 + c8) = o;
    }
}

// ---------------------------------------------------------------------------
// K1 (new): raw scaled scores S = Q K^T / 32, pure-bf16 m97-style.
// 128x128 tile, BK=64, 512 threads = 8 waves (4q x 2k).
// global_load_lds width-16 staging into linear [128][64] LDS, double-buffered.
// ---------------------------------------------------------------------------
__global__ __launch_bounds__(512, 4)
void scores_bf_kernel(const bf16* __restrict__ Qbf, const bf16* __restrict__ Kbf,
                      const int* __restrict__ qlens, const int* __restrict__ klens,
                      float* __restrict__ Wout)
{
    const int b  = blockIdx.z;
    const int q0 = blockIdx.y * 128;
    const int k0 = blockIdx.x * 128;
    if (k0 > q0 + 127) return;                       // above causal diagonal
    const int qlen = qlens[b], klen = klens[b];
    if (q0 >= qlen || k0 >= klen) return;            // fully masked

    __shared__ __align__(16) bf16 Qs[2][128][64];
    __shared__ __align__(16) bf16 Ks[2][128][64];

    const int tid  = threadIdx.x;
    const int lane = tid & 63;
    const int w    = tid >> 6;
    const int wq   = w >> 1, wk = w & 1;

    const bf16* Qb = Qbf + (size_t)b * SQ_ * D_ + (size_t)q0 * D_;
    const bf16* Kb = Kbf + (size_t)b * SK_ * D_ + (size_t)k0 * D_;

    const int r0 = tid >> 3;                         // 0..63
    const int c0 = (tid & 7) << 3;                   // 0,8,..,56 (bf16 elems)

    auto stage = [&](int buf, int d0) {
        gload16(Qb + (size_t)r0 * D_ + d0 + c0,        &Qs[buf][r0][c0]);
        gload16(Qb + (size_t)(r0 + 64) * D_ + d0 + c0, &Qs[buf][r0 + 64][c0]);
        gload16(Kb + (size_t)r0 * D_ + d0 + c0,        &Ks[buf][r0][c0]);
        gload16(Kb + (size_t)(r0 + 64) * D_ + d0 + c0, &Ks[buf][r0 + 64][c0]);
    };

    f32x4 acc[2][4] = {};                            // wave tile 32x64

    stage(0, 0);
    __syncthreads();

    for (int it = 0; it < 16; ++it) {
        const int cur = it & 1;
        if (it < 15) stage(cur ^ 1, (it + 1) * 64);
        #pragma unroll
        for (int kk = 0; kk < 2; ++kk) {
            const int koff = kk * 32 + ((lane >> 4) << 3);
            bf16x8 a[2], bb[4];
            #pragma unroll
            for (int m = 0; m < 2; ++m)
                a[m] = *(const bf16x8*)&Qs[cur][32 * wq + 16 * m + (lane & 15)][koff];
            #pragma unroll
            for (int n = 0; n < 4; ++n)
                bb[n] = *(const bf16x8*)&Ks[cur][64 * wk + 16 * n + (lane & 15)][koff];
            #pragma unroll
            for (int m = 0; m < 2; ++m)
                #pragma unroll
                for (int n = 0; n < 4; ++n)
                    acc[m][n] = __builtin_amdgcn_mfma_f32_16x16x32_bf16(a[m], bb[n], acc[m][n], 0, 0, 0);
        }
        __syncthreads();
    }

    float* Wb = Wout + (size_t)b * SQ_ * SK_;
    const int rb = q0 + 32 * wq + ((lane >> 4) << 2);
    const int cb = k0 + 64 * wk + (lane & 15);
    #pragma unroll
    for (int m = 0; m < 2; ++m)
        #pragma unroll
        for (int n = 0; n < 4; ++n)
            #pragma unroll
            for (int r = 0; r < 4; ++r)
                Wb[(size_t)(rb + 16 * m + r) * SK_ + (cb + 16 * n)] = acc[m][n][r] * 0.03125f;
}

// ---------------------------------------------------------------------------
// K2: masked softmax in place; also emits a bf16 copy of W for K3's A-operand
// when wbf != null. One block per (b,q) row; reads bounded by kmax.
// ---------------------------------------------------------------------------
__global__ __launch_bounds__(256)
void softmax_kernel(const int* __restrict__ qlens, const int* __restrict__ klens,
                    float* __restrict__ W, bf16* __restrict__ Wbf)
{
    const int bq = blockIdx.x;          // b*SQ + q
    const int b  = bq >> 11;
    const int q  = bq & 2047;
    const int qlen = qlens[b], klen = klens[b];
    int kmax = 0;
    if (q < qlen) kmax = min(klen, q + 1);

    float4* row = (float4*)(W + (size_t)bq * SK_);
    const int tid = threadIdx.x;

    float4 x[2];
    float m = -INFINITY;
    #pragma unroll
    for (int i = 0; i < 2; ++i) {
        int v4 = tid + i * 256;
        int kb = v4 << 2;
        if (kb < kmax) x[i] = row[v4];
        else           x[i] = make_float4(-INFINITY, -INFINITY, -INFINITY, -INFINITY);
        float* xe = (float*)&x[i];
        #pragma unroll
        for (int e = 0; e < 4; ++e) {
            if (kb + e >= kmax) xe[e] = -INFINITY;
            m = fmaxf(m, xe[e]);
        }
    }
    #pragma unroll
    for (int off = 32; off > 0; off >>= 1) m = fmaxf(m, __shfl_xor(m, off, 64));
    __shared__ float red[4];
    if ((tid & 63) == 0) red[tid >> 6] = m;
    __syncthreads();
    m = fmaxf(fmaxf(red[0], red[1]), fmaxf(red[2], red[3]));
    __syncthreads();

    float sum = 0.f;
    #pragma unroll
    for (int i = 0; i < 2; ++i) {
        float* xe = (float*)&x[i];
        #pragma unroll
        for (int e = 0; e < 4; ++e) {
            float ev = (xe[e] == -INFINITY) ? 0.f : __expf(xe[e] - m);
            xe[e] = ev;
            sum += ev;
        }
    }
    #pragma unroll
    for (int off = 32; off > 0; off >>= 1) sum += __shfl_xor(sum, off, 64);
    if ((tid & 63) == 0) red[tid >> 6] = sum;
    __syncthreads();
    sum = red[0] + red[1] + red[2] + red[3];

    const float inv = (sum > 0.f) ? (1.f / sum) : 0.f;
    #pragma unroll
    for (int i = 0; i < 2; ++i) {
        float* xe = (float*)&x[i];
        float4 o = { xe[0] * inv, xe[1] * inv, xe[2] * inv, xe[3] * inv };
        row[tid + i * 256] = o;
        if (Wbf) {
            bf16x4 ob = { (bf16)o.x, (bf16)o.y, (bf16)o.z, (bf16)o.w };
            *(bf16x4*)(Wbf + (size_t)bq * SK_ + ((size_t)(tid + i * 256) << 2)) = ob;
        }
    }
}

// ---------------------------------------------------------------------------
// K3 (new): context = Wbf @ VT^T, pure-bf16, same structure as K1.
// A = Wbf[q][k], B = VT[n][k] (pre-transposed), k bounded by mask.
// Fully-masked q-stripes take a zero-store fast path.
// ---------------------------------------------------------------------------
__global__ __launch_bounds__(512, 4)
void context_bf_kernel(const bf16* __restrict__ Wbf, const bf16* __restrict__ VT,
                       const int* __restrict__ qlens, const int* __restrict__ klens,
                       float* __restrict__ Out)
{
    const int b  = blockIdx.z;
    const int q0 = blockIdx.y * 128;
    const int n0 = blockIdx.x * 128;
    const int tid  = threadIdx.x;
    const int qlen = qlens[b];

    float* Ob = Out + (size_t)b * SQ_ * DV_;
    if (q0 >= qlen) {                                // all rows masked -> zeros
        float4 z = make_float4(0.f, 0.f, 0.f, 0.f);
        #pragma unroll
        for (int i = 0; i < 8; ++i) {
            int s  = tid + i * 512;                  // 128 rows x 32 float4
            int r  = s >> 5;
            int c4 = (s & 31) << 2;
            *(float4*)(Ob + (size_t)(q0 + r) * DV_ + n0 + c4) = z;
        }
        return;
    }

    const int klen = klens[b];
    const int kend = min(q0 + 128, (klen + 63) & ~63);
    const int nk   = kend >> 6;                      // >= 1

    __shared__ __align__(16) bf16 Ws[2][128][64];
    __shared__ __align__(16) bf16 Vs[2][128][64];

    const int lane = tid & 63;
    const int w    = tid >> 6;
    const int wq   = w >> 1, wn = w & 1;

    const bf16* Wb = Wbf + (size_t)b * SQ_ * SK_ + (size_t)q0 * SK_;
    const bf16* Vb = VT  + (size_t)b * DV_ * SK_ + (size_t)n0 * SK_;

    const int r0 = tid >> 3;
    const int c0 = (tid & 7) << 3;

    auto stage = [&](int buf, int kk0) {
        gload16(Wb + (size_t)r0 * SK_ + kk0 + c0,        &Ws[buf][r0][c0]);
        gload16(Wb + (size_t)(r0 + 64) * SK_ + kk0 + c0, &Ws[buf][r0 + 64][c0]);
        gload16(Vb + (size_t)r0 * SK_ + kk0 + c0,        &Vs[buf][r0][c0]);
        gload16(Vb + (size_t)(r0 + 64) * SK_ + kk0 + c0, &Vs[buf][r0 + 64][c0]);
    };

    f32x4 acc[2][4] = {};

    stage(0, 0);
    __syncthreads();

    for (int it = 0; it < nk; ++it) {
        const int cur = it & 1;
        if (it + 1 < nk) stage(cur ^ 1, (it + 1) * 64);
        #pragma unroll
        for (int kk = 0; kk < 2; ++kk) {
            const int koff = kk * 32 + ((lane >> 4) << 3);
            bf16x8 a[2], bb[4];
            #pragma unroll
            for (int m = 0; m < 2; ++m)
                a[m] = *(const bf16x8*)&Ws[cur][32 * wq + 16 * m + (lane & 15)][koff];
            #pragma unroll
            for (int n = 0; n < 4; ++n)
                bb[n] = *(const bf16x8*)&Vs[cur][64 * wn + 16 * n + (lane & 15)][koff];
            #pragma unroll
            for (int m = 0; m < 2; ++m)
                #pragma unroll
                for (int n = 0; n < 4; ++n)
                    acc[m][n] = __builtin_amdgcn_mfma_f32_16x16x32_bf16(a[m], bb[n], acc[m][n], 0, 0, 0);
        }
        __syncthreads();
    }

    const int rb = q0 + 32 * wq + ((lane >> 4) << 2);
    const int cb = n0 + 64 * wn + (lane & 15);
    #pragma unroll
    for (int m = 0; m < 2; ++m)
        #pragma unroll
        for (int n = 0; n < 4; ++n)
            #pragma unroll
            for (int r = 0; r < 4; ++r)
                Ob[(size_t)(rb + 16 * m + r) * DV_ + (cb + 16 * n)] = acc[m][n][r];
}

// ---------------------------------------------------------------------------
// Fallback path (previous verified kernels, fp32 operands), used only if the
// workspace is too small for the bf16 staging buffers.
// ---------------------------------------------------------------------------
__global__ __launch_bounds__(512, 4)
void scores_kernel(const float* __restrict__ Q, const float* __restrict__ K,
                   const int* __restrict__ qlens, const int* __restrict__ klens,
                   float* __restrict__ Wout)
{
    const int b  = blockIdx.z;
    const int q0 = blockIdx.y * 128;
    const int k0 = blockIdx.x * 128;
    if (k0 > q0 + 127) return;
    const int qlen = qlens[b], klen = klens[b];
    if (q0 >= qlen || k0 >= klen) return;

    __shared__ __align__(16) bf16 Qs[2][128][72];
    __shared__ __align__(16) bf16 Ks[2][128][72];

    const int tid  = threadIdx.x;
    const int lane = tid & 63;
    const int w    = tid >> 6;
    const int wq   = w >> 1, wk = w & 1;

    const float* Qb = Q + (size_t)b * SQ_ * D_;
    const float* Kb = K + (size_t)b * SK_ * D_;

    float4 qreg[4], kreg[4];
    int srow[4], sc4[4];
    #pragma unroll
    for (int i = 0; i < 4; ++i) {
        int s = tid + i * 512;
        srow[i] = s >> 4;
        sc4[i]  = (s & 15) << 2;
    }

    auto load_tile = [&](int d0) {
        #pragma unroll
        for (int i = 0; i < 4; ++i) {
            qreg[i] = *(const float4*)(Qb + (size_t)(q0 + srow[i]) * D_ + d0 + sc4[i]);
            kreg[i] = *(const float4*)(Kb + (size_t)(k0 + srow[i]) * D_ + d0 + sc4[i]);
        }
    };
    auto store_tile = [&](int buf) {
        #pragma unroll
        for (int i = 0; i < 4; ++i) {
            bf16x4 qb = { (bf16)qreg[i].x, (bf16)qreg[i].y, (bf16)qreg[i].z, (bf16)qreg[i].w };
            bf16x4 kb = { (bf16)kreg[i].x, (bf16)kreg[i].y, (bf16)kreg[i].z, (bf16)kreg[i].w };
            *(bf16x4*)&Qs[buf][srow[i]][sc4[i]] = qb;
            *(bf16x4*)&Ks[buf][srow[i]][sc4[i]] = kb;
        }
    };

    f32x4 acc[2][4] = {};
    load_tile(0);
    store_tile(0);
    __syncthreads();

    for (int it = 0; it < 16; ++it) {
        const int cur = it & 1;
        if (it < 15) load_tile((it + 1) * 64);
        #pragma unroll
        for (int kk = 0; kk < 2; ++kk) {
            const int koff = kk * 32 + ((lane >> 4) << 3);
            bf16x8 a[2], bb[4];
            #pragma unroll
            for (int m = 0; m < 2; ++m)
                a[m] = *(const bf16x8*)&Qs[cur][32 * wq + 16 * m + (lane & 15)][koff];
            #pragma unroll
            for (int n = 0; n < 4; ++n)
                bb[n] = *(const bf16x8*)&Ks[cur][64 * wk + 16 * n + (lane & 15)][koff];
            #pragma unroll
            for (int m = 0; m < 2; ++m)
                #pragma unroll
                for (int n = 0; n < 4; ++n)
                    acc[m][n] = __builtin_amdgcn_mfma_f32_16x16x32_bf16(a[m], bb[n], acc[m][n], 0, 0, 0);
        }
        if (it < 15) store_tile(1 - cur);
        __syncthreads();
    }

    float* Wb = Wout + (size_t)b * SQ_ * SK_;
    const int rb = q0 + 32 * wq + ((lane >> 4) << 2);
    const int cb = k0 + 64 * wk + (lane & 15);
    #pragma unroll
    for (int m = 0; m < 2; ++m)
        #pragma unroll
        for (int n = 0; n < 4; ++n)
            #pragma unroll
            for (int r = 0; r < 4; ++r)
                Wb[(size_t)(rb + 16 * m + r) * SK_ + (cb + 16 * n)] = acc[m][n][r] * 0.03125f;
}

__global__ __launch_bounds__(512, 4)
void context_kernel(const float* __restrict__ W, const float* __restrict__ V,
                    const int* __restrict__ klens, float* __restrict__ Out)
{
    const int b  = blockIdx.z;
    const int q0 = blockIdx.y * 128;
    const int n0 = blockIdx.x * 128;
    const int klen = klens[b];
    const int kend = min(q0 + 128, (klen + 63) & ~63);
    const int nk   = kend >> 6;

    __shared__ __align__(16) bf16 Ws[2][128][72];
    __shared__ __align__(16) bf16 Vs[2][128][72];

    const int tid  = threadIdx.x;
    const int lane = tid & 63;
    const int w    = tid >> 6;
    const int wq   = w >> 1, wn = w & 1;

    const float* Wb = W + (size_t)b * SQ_ * SK_;
    const float* Vb = V + (size_t)b * SK_ * DV_;

    float4 wreg[4];
    float  vreg[2][8];
    int srow[4], sc4[4], vn[2], voct[2];
    #pragma unroll
    for (int i = 0; i < 4; ++i) {
        int s = tid + i * 512;
        srow[i] = s >> 4;
        sc4[i]  = (s & 15) << 2;
    }
    #pragma unroll
    for (int i = 0; i < 2; ++i) {
        int t = tid + i * 512;
        vn[i]   = t & 127;
        voct[i] = t >> 7;
    }

    auto load_tile = [&](int kk0) {
        #pragma unroll
        for (int i = 0; i < 4; ++i)
            wreg[i] = *(const float4*)(Wb + (size_t)(q0 + srow[i]) * SK_ + kk0 + sc4[i]);
        #pragma unroll
        for (int i = 0; i < 2; ++i)
            #pragma unroll
            for (int j = 0; j < 8; ++j)
                vreg[i][j] = Vb[(size_t)(kk0 + voct[i] * 8 + j) * DV_ + n0 + vn[i]];
    };
    auto store_tile = [&](int buf) {
        #pragma unroll
        for (int i = 0; i < 4; ++i) {
            bf16x4 wb = { (bf16)wreg[i].x, (bf16)wreg[i].y, (bf16)wreg[i].z, (bf16)wreg[i].w };
            *(bf16x4*)&Ws[buf][srow[i]][sc4[i]] = wb;
        }
        #pragma unroll
        for (int i = 0; i < 2; ++i) {
            bf16x8 vb = { (bf16)vreg[i][0], (bf16)vreg[i][1], (bf16)vreg[i][2], (bf16)vreg[i][3],
                          (bf16)vreg[i][4], (bf16)vreg[i][5], (bf16)vreg[i][6], (bf16)vreg[i][7] };
            *(bf16x8*)&Vs[buf][vn[i]][voct[i] * 8] = vb;
        }
    };

    f32x4 acc[2][4] = {};
    load_tile(0);
    store_tile(0);
    __syncthreads();

    for (int it = 0; it < nk; ++it) {
        const int cur = it & 1;
        if (it + 1 < nk) load_tile((it + 1) * 64);
        #pragma unroll
        for (int kk = 0; kk < 2; ++kk) {
            const int koff = kk * 32 + ((lane >> 4) << 3);
            bf16x8 a[2], bb[4];
            #pragma unroll
            for (int m = 0; m < 2; ++m)
                a[m] = *(const bf16x8*)&Ws[cur][32 * wq + 16 * m + (lane & 15)][koff];
            #pragma unroll
            for (int n = 0; n < 4; ++n)
                bb[n] = *(const bf16x8*)&Vs[cur][64 * wn + 16 * n + (lane & 15)][koff];
            #pragma unroll
            for (int m = 0; m < 2; ++m)
                #pragma unroll
                for (int n = 0; n < 4; ++n)
                    acc[m][n] = __builtin_amdgcn_mfma_f32_16x16x32_bf16(a[m], bb[n], acc[m][n], 0, 0, 0);
        }
        if (it + 1 < nk) store_tile(1 - cur);
        __syncthreads();
    }

    float* Ob = Out + (size_t)b * SQ_ * DV_;
    const int rb = q0 + 32 * wq + ((lane >> 4) << 2);
    const int cb = n0 + 64 * wn + (lane & 15);
    #pragma unroll
    for (int m = 0; m < 2; ++m)
        #pragma unroll
        for (int n = 0; n < 4; ++n)
            #pragma unroll
            for (int r = 0; r < 4; ++r)
                Ob[(size_t)(rb + 16 * m + r) * DV_ + (cb + 16 * n)] = acc[m][n][r];
}

extern "C" void kernel_launch(void* const* d_in, const int* in_sizes, int n_in,
                              void* d_out, int out_size, void* d_ws, size_t ws_size,
                              hipStream_t stream) {
    (void)in_sizes; (void)n_in; (void)out_size;
    const float* Q     = (const float*)d_in[0];
    const float* K     = (const float*)d_in[1];
    const float* V     = (const float*)d_in[2];
    const int*   qlens = (const int*)d_in[3];
    const int*   klens = (const int*)d_in[4];

    float* ctx = (float*)d_out;                          // (B,SQ,DV) first
    float* wts = ctx + (size_t)B_ * SQ_ * DV_;           // then (B,SQ,SK)

    const size_t nQ = (size_t)B_ * SQ_ * D_;             // 16.78M elems
    const size_t nK = (size_t)B_ * SK_ * D_;
    const size_t nV = (size_t)B_ * SK_ * DV_;
    const size_t nW = (size_t)B_ * SQ_ * SK_;
    const size_t ws_need = (nQ + nK + nV + nW) * sizeof(bf16);  // 160 MB

    if (d_ws && ws_size >= ws_need) {
        bf16* qbf = (bf16*)d_ws;
        bf16* kbf = qbf + nQ;
        bf16* vbt = kbf + nK;                            // V transposed (B,DV,SK)
        bf16* wbf = vbt + nV;                            // bf16 copy of weights

        convert_kernel<<<dim3((unsigned)(nQ / (256 * 8)), 2), 256, 0, stream>>>(Q, K, qbf, kbf);
        convVT_kernel<<<dim3(SK_ / 64, DV_ / 64, B_), 256, 0, stream>>>(V, vbt);

        dim3 g1(SK_ / 128, SQ_ / 128, B_);
        scores_bf_kernel<<<g1, 512, 0, stream>>>(qbf, kbf, qlens, klens, wts);

        softmax_kernel<<<dim3(B_ * SQ_), 256, 0, stream>>>(qlens, klens, wts, wbf);

        dim3 g3(DV_ / 128, SQ_ / 128, B_);
        context_bf_kernel<<<g3, 512, 0, stream>>>(wbf, vbt, qlens, klens, ctx);
    } else {
        // Fallback: previous verified fp32-staging path.
        dim3 g1(SK_ / 128, SQ_ / 128, B_);
        scores_kernel<<<g1, 512, 0, stream>>>(Q, K, qlens, klens, wts);

        softmax_kernel<<<dim3(B_ * SQ_), 256, 0, stream>>>(qlens, klens, wts, (bf16*)nullptr);

        dim3 g3(DV_ / 128, SQ_ / 128, B_);
        context_kernel<<<g3, 512, 0, stream>>>(wts, V, klens, ctx);
    }
}